// Round 1
// baseline (22228.831 us; speedup 1.0000x reference)
//
#include <hip/hip_runtime.h>
#include <stdint.h>

// BiLSTM-CRF on gfx950 — fp32 inputs (jax default). All math fp32 (validated
// R4 absmax 0.0). R7 = R6 with lstm_rec restructured: 512 threads x 2 gate
// rows/thread (2 waves/SIMD -> 256 VGPR budget). Halves LDS h-broadcast
// instructions, 84 resident k/row in regs + 12 k/row in LDS + 160 k/row
// streamed with 6-deep float4 prefetch pipeline and 2 acc chains/row.

#define T_ 256
#define B_ 64
#define EPAD 304
#define KTAG 20
#define TB_ (T_ * B_)

// lstm_rec weight partition (per gate row of 256 k):
#define RRES 84                      // k resident in VGPRs per row
#define LKW 12                       // k staged in LDS per row
#define NQS 40                       // streamed float4 quads per row (160 k)
#define DPF 6                        // prefetch pipeline depth (float4 pairs)
#define WLDS_OFF (2 * RRES * 2 * 512)                // 172032 floats
#define WSTR_OFF (WLDS_OFF + 2 * LKW * 1024)         // 196608 floats
// total whhL floats = WSTR_OFF + 2*2*NQS*512*4 = 524288 (2 MiB)

// ---------------- prep ----------------

__global__ void prep_embed(const int* __restrict__ x, const float* __restrict__ emb,
                           float* __restrict__ xsA) {
  int r = blockIdx.x;
  int tok = x[r];
  const float* src = emb + (size_t)tok * 300;
  for (int e = threadIdx.x; e < EPAD; e += 64)
    xsA[(size_t)r * EPAD + e] = (e < 300) ? src[e] : 0.f;
}

// B0t[2048][304]: Wih0 [2*1024,300] K-padded to 304.
__global__ void prep_b0t(const float* __restrict__ Wih0, float* __restrict__ B0t) {
  int idx = blockIdx.x * 256 + threadIdx.x;
  if (idx >= 2048 * EPAD) return;
  int n = idx / EPAD, k = idx % EPAD;
  B0t[idx] = (k < 300) ? Wih0[(size_t)n * 300 + k] : 0.f;
}

// Bot[64][512]: W_out [20,512] rows padded to 64; biaso[64] likewise.
__global__ void prep_bot64(const float* __restrict__ Wout, float* __restrict__ Bot,
                           const float* __restrict__ bout, float* __restrict__ biaso) {
  int idx = blockIdx.x * 256 + threadIdx.x;   // 64*512
  int n = idx >> 9, k = idx & 511;
  Bot[idx] = (n < KTAG) ? Wout[(size_t)n * 512 + k] : 0.f;
  if (idx < 64) biaso[idx] = (idx < KTAG) ? bout[idx] : 0.f;
}

// Whh [2][1024 rows][256 k] -> whhL for the 512-thread/2-row lstm kernel.
// Thread tg (0..511) owns rows: gt = tg&3, jj = tg>>2;
//   row(r=0) = gt*256 + jj, row(r=1) = gt*256 + jj + 128.
// Regions: resident [d][k<84][r][tg]; LDS-staged [d][q3][r][tg][4] (k 84..95);
// streamed [d][r][q][tg][4] (k 96..255).
__global__ void prep_whh2(const float* __restrict__ Whh, float* __restrict__ whhL) {
  int idx = blockIdx.x * 256 + threadIdx.x;   // 524288
  int d = idx >> 18, rem = idx & 262143, k = rem >> 10, row = rem & 1023;
  float v = Whh[(size_t)d * 262144 + (size_t)row * 256 + k];
  int gt = row >> 8, jr = row & 255, r = jr >> 7, jj = jr & 127;
  int tg = jj * 4 + gt;
  if (k < RRES) {
    whhL[((size_t)(d * RRES + k) * 2 + r) * 512 + tg] = v;
  } else if (k < RRES + LKW) {
    int kk = k - RRES, q3 = kk >> 2, e = kk & 3;
    whhL[WLDS_OFF + (size_t)(((d * 3 + q3) * 2 + r) * 512 + tg) * 4 + e] = v;
  } else {
    int kk = k - RRES - LKW, q = kk >> 2, e = kk & 3;
    whhL[WSTR_OFF + (size_t)(((d * 2 + r) * NQS + q) * 512 + tg) * 4 + e] = v;
  }
}

// ---------------- fp32 GEMM: C[M,N] = A[M,K] * Bt[N,K]^T + bias ----------------
// 64x64 tile, BK=16, 256 threads, 4x4 outputs/thread (R4-validated).
__global__ __launch_bounds__(256) void gemm_f32(
    const float* __restrict__ A, int lda, const float* __restrict__ Bt, int ldb,
    float* __restrict__ C, int ldc, const float* __restrict__ bias,
    int ntn, int K) {
  const int tm = blockIdx.x / ntn, tn = blockIdx.x % ntn;
  const int m0 = tm * 64, n0 = tn * 64;
  __shared__ __align__(16) float As[16][64];
  __shared__ __align__(16) float Bs[16][64];
  const int tid = threadIdx.x;
  const int mm = tid >> 2, kq = (tid & 3) * 4;
  const int tx = tid & 15, ty = tid >> 4;
  float acc[4][4] = {};
  for (int k0 = 0; k0 < K; k0 += 16) {
    float4 av = *(const float4*)&A[(size_t)(m0 + mm) * lda + k0 + kq];
    float4 bv = *(const float4*)&Bt[(size_t)(n0 + mm) * ldb + k0 + kq];
    __syncthreads();                       // guard prev-iter LDS reads
    As[kq + 0][mm] = av.x; As[kq + 1][mm] = av.y;
    As[kq + 2][mm] = av.z; As[kq + 3][mm] = av.w;
    Bs[kq + 0][mm] = bv.x; Bs[kq + 1][mm] = bv.y;
    Bs[kq + 2][mm] = bv.z; Bs[kq + 3][mm] = bv.w;
    __syncthreads();
#pragma unroll
    for (int kk = 0; kk < 16; ++kk) {
      float4 a4 = *(const float4*)&As[kk][ty * 4];
      float4 b4 = *(const float4*)&Bs[kk][tx * 4];
      acc[0][0] += a4.x * b4.x; acc[0][1] += a4.x * b4.y;
      acc[0][2] += a4.x * b4.z; acc[0][3] += a4.x * b4.w;
      acc[1][0] += a4.y * b4.x; acc[1][1] += a4.y * b4.y;
      acc[1][2] += a4.y * b4.z; acc[1][3] += a4.y * b4.w;
      acc[2][0] += a4.z * b4.x; acc[2][1] += a4.z * b4.y;
      acc[2][2] += a4.z * b4.z; acc[2][3] += a4.z * b4.w;
      acc[3][0] += a4.w * b4.x; acc[3][1] += a4.w * b4.y;
      acc[3][2] += a4.w * b4.z; acc[3][3] += a4.w * b4.w;
    }
  }
#pragma unroll
  for (int i = 0; i < 4; ++i)
#pragma unroll
    for (int j = 0; j < 4; ++j)
      C[(size_t)(m0 + ty * 4 + i) * ldc + n0 + tx * 4 + j] =
          acc[i][j] + bias[n0 + tx * 4 + j];
}

// ---------------- persistent LSTM recurrence (fp32) ----------------
// One WG (512 threads, 8 waves -> 2 waves/SIMD, 256 VGPR budget) per (b,dir).
// Thread tg owns TWO gate rows: gt*256+jj and gt*256+jj+128 (gt=tg&3, jj=tg>>2)
// so each h float4 LDS read feeds 8 FMAs. k-split per row: 84 resident VGPR,
// 12 in LDS (staged once), 160 streamed from L2 with DPF-deep prefetch and
// 2 accumulator chains per row. One barrier/step (double-buffered h).
__global__ __launch_bounds__(512, 2) void lstm_rec(
    const float* __restrict__ xg, const float* __restrict__ whhL,
    float* __restrict__ out, const int* __restrict__ lens) {
  const int wg = blockIdx.x, dir = wg & 1, b = wg >> 1;
  const int len = lens[b];
  const int tg = threadIdx.x;               // 0..511
  const int gt = tg & 3, jj = tg >> 2;      // jj 0..127
  const int row0 = gt * 256 + jj;
  const int row1 = row0 + 128;

  // resident weights: k = 0..83 for both rows
  float w0[RRES], w1[RRES];
#pragma unroll
  for (int k = 0; k < RRES; ++k) {
    w0[k] = whhL[((size_t)(dir * RRES + k) * 2 + 0) * 512 + tg];
    w1[k] = whhL[((size_t)(dir * RRES + k) * 2 + 1) * 512 + tg];
  }

  __shared__ __align__(16) float hsd[2][256];
  __shared__ __align__(16) float4 wlds4[3][2][512];   // 48 KiB, k = 84..95
  for (int i = tg; i < 3 * 2 * 512; i += 512) {
    int q3 = i >> 10, rr = (i >> 9) & 1, tt = i & 511;
    wlds4[q3][rr][tt] =
        *(const float4*)&whhL[WLDS_OFF + (size_t)(((dir * 3 + q3) * 2 + rr) * 512 + tt) * 4];
  }
  if (tg < 256) hsd[0][tg] = 0.f;
  float c0 = 0.f, c1 = 0.f;
  __syncthreads();

  // streamed bases: k = 96..255, layout [dir][r][q][tg][4]
  const float* sp0 = whhL + WSTR_OFF + ((size_t)(dir * 2 + 0) * NQS) * 2048 + tg * 4;
  const float* sp1 = whhL + WSTR_OFF + ((size_t)(dir * 2 + 1) * NQS) * 2048 + tg * 4;

  const int lane = tg & 63, qb = lane & ~3;

  for (int s = 0; s < len; ++s) {
    const int t = dir ? (len - 1 - s) : s;   // bwd consumes & writes reversed pos
    const int rp = t * B_ + b;
    float xv0 = xg[(size_t)rp * 2048 + dir * 1024 + row0];
    float xv1 = xg[(size_t)rp * 2048 + dir * 1024 + row1];
    const float4* Hr = (const float4*)hsd[s & 1];

    // prologue: fill prefetch pipeline (latency covered by resident FMAs)
    float4 s0[DPF], s1[DPF];
#pragma unroll
    for (int d = 0; d < DPF; ++d) {
      s0[d] = *(const float4*)(sp0 + (size_t)d * 2048);
      s1[d] = *(const float4*)(sp1 + (size_t)d * 2048);
    }

    float acc0[2] = {0.f, 0.f}, acc1[2] = {0.f, 0.f};

    // resident k = 0..83 (21 quads)
#pragma unroll
    for (int p = 0; p < RRES / 4; ++p) {
      float4 h4 = Hr[p];
      acc0[p & 1] += w0[4 * p] * h4.x + w0[4 * p + 1] * h4.y +
                     w0[4 * p + 2] * h4.z + w0[4 * p + 3] * h4.w;
      acc1[p & 1] += w1[4 * p] * h4.x + w1[4 * p + 1] * h4.y +
                     w1[4 * p + 2] * h4.z + w1[4 * p + 3] * h4.w;
    }
    // LDS-staged k = 84..95 (3 quads)
#pragma unroll
    for (int q3 = 0; q3 < 3; ++q3) {
      float4 h4 = Hr[RRES / 4 + q3];
      float4 wl0 = wlds4[q3][0][tg];
      float4 wl1 = wlds4[q3][1][tg];
      acc0[q3 & 1] += wl0.x * h4.x + wl0.y * h4.y + wl0.z * h4.z + wl0.w * h4.w;
      acc1[q3 & 1] += wl1.x * h4.x + wl1.y * h4.y + wl1.z * h4.z + wl1.w * h4.w;
    }
    // streamed k = 96..255 (40 quads), software-pipelined
#pragma unroll
    for (int q = 0; q < NQS; ++q) {
      float4 h4 = Hr[RRES / 4 + 3 + q];
      float4 w0v = s0[q % DPF];
      float4 w1v = s1[q % DPF];
      if (q + DPF < NQS) {
        s0[q % DPF] = *(const float4*)(sp0 + (size_t)(q + DPF) * 2048);
        s1[q % DPF] = *(const float4*)(sp1 + (size_t)(q + DPF) * 2048);
      }
      acc0[q & 1] += w0v.x * h4.x + w0v.y * h4.y + w0v.z * h4.z + w0v.w * h4.w;
      acc1[q & 1] += w1v.x * h4.x + w1v.y * h4.y + w1v.z * h4.z + w1v.w * h4.w;
    }

    float a0 = acc0[0] + acc0[1] + xv0;
    float a1 = acc1[0] + acc1[1] + xv1;
    float u01 = __shfl(a0, qb | 1), u02 = __shfl(a0, qb | 2), u03 = __shfl(a0, qb | 3);
    float u11 = __shfl(a1, qb | 1), u12 = __shfl(a1, qb | 2), u13 = __shfl(a1, qb | 3);
    if (gt == 0) {
      float si0 = 1.f / (1.f + expf(-a0));    // i
      float sf0 = 1.f / (1.f + expf(-u01));   // f
      float so0 = 1.f / (1.f + expf(-u03));   // o
      c0 = sf0 * c0 + si0 * tanhf(u02);       // g = u02
      float h0v = so0 * tanhf(c0);
      float si1 = 1.f / (1.f + expf(-a1));
      float sf1 = 1.f / (1.f + expf(-u11));
      float so1 = 1.f / (1.f + expf(-u13));
      c1 = sf1 * c1 + si1 * tanhf(u12);
      float h1v = so1 * tanhf(c1);
      float* Hw = hsd[(s + 1) & 1];
      Hw[jj] = h0v;
      Hw[jj + 128] = h1v;
      out[(size_t)rp * 512 + dir * 256 + jj] = h0v;
      out[(size_t)rp * 512 + dir * 256 + jj + 128] = h1v;
    }
    __syncthreads();                          // one barrier per step
  }
  for (int t = len; t < T_; ++t)              // pack_padded: padded outputs zero
    if (gt == 0) {
      out[(size_t)(t * B_ + b) * 512 + dir * 256 + jj] = 0.f;
      out[(size_t)(t * B_ + b) * 512 + dir * 256 + jj + 128] = 0.f;
    }
}

// ---------------- Viterbi (one wave per batch; ref fp-op order) ----------------
__global__ __launch_bounds__(64) void viterbi(
    const float* __restrict__ emis, const float* __restrict__ trans,
    const float* __restrict__ startv, const float* __restrict__ endv,
    const int* __restrict__ lens, int* __restrict__ outp) {
  int b = blockIdx.x, lane = threadIdx.x;
  __shared__ float tr[KTAG * KTAG];
  __shared__ float fin[KTAG];
  __shared__ unsigned char hist[T_ * KTAG];
  for (int i = lane; i < KTAG * KTAG; i += 64) tr[i] = trans[i];
  int len = lens[b];
  float score = (lane < KTAG) ? startv[lane] + emis[(size_t)b * 64 + lane] : -3e38f;
  __syncthreads();
  for (int t = 1; t < len; ++t) {
    float e = (lane < KTAG) ? emis[(size_t)(t * B_ + b) * 64 + lane] : 0.f;
    float best = -3e38f; int bp = 0;
    for (int p = 0; p < KTAG; ++p) {         // ascending p + strict '>': first-index
      float cand = (__shfl(score, p) + tr[p * KTAG + lane]) + e;  // ref op order
      if (cand > best) { best = cand; bp = p; }
    }
    if (lane < KTAG) { score = best; hist[t * KTAG + lane] = (unsigned char)bp; }
  }
  if (lane < KTAG) fin[lane] = score + endv[lane];
  __syncthreads();
  if (lane == 0) {
    float bb = -3e38f; int tag = 0;
    for (int p = 0; p < KTAG; ++p)
      if (fin[p] > bb) { bb = fin[p]; tag = p; }
    for (int t = len - 1; t >= 1; --t) {
      outp[t * B_ + b] = tag;
      tag = hist[t * KTAG + tag];
    }
    outp[b] = tag;
  }
  for (int t = len + lane; t < T_; t += 64) outp[t * B_ + b] = 0;
}

// ---------------- diagnostics (slim) ----------------
__global__ void sentinel_fill(int* __restrict__ outp, int val) {
  int i = blockIdx.x * 256 + threadIdx.x;
  if (i < TB_) outp[i] = val;
}
__global__ void diag_init(int* __restrict__ f) { if (threadIdx.x == 0) f[0] = 0; }
__global__ void check_nan(const float* __restrict__ p, long n, int* __restrict__ f) {
  long i0 = (long)blockIdx.x * 256 + threadIdx.x;
  int bad = 0;
  for (long i = i0; i < n; i += (long)gridDim.x * 256)
    if (!(fabsf(p[i]) <= 1e8f)) bad = 1;
  if (bad) atomicOr(&f[0], 1);
}
__global__ void verdict(const int* __restrict__ f, int* __restrict__ outp) {
  if (f[0]) outp[threadIdx.x] = -4096;
}

// ---------------- host ----------------

extern "C" void kernel_launch(void* const* d_in, const int* in_sizes, int n_in,
                              void* d_out, int out_size, void* d_ws, size_t ws_size,
                              hipStream_t stream) {
  int* outp = (int*)d_out;

  static const int exp_sizes[14] = {16384, 64, 15000000, 614400, 524288, 2048,
                                    1048576, 524288, 2048, 10240, 20, 400, 20, 20};
  int badi = (n_in == 14) ? -1 : 14;
  if (badi < 0)
    for (int i = 0; i < 14; ++i)
      if (in_sizes[i] != exp_sizes[i]) { badi = i; break; }
  if (badi >= 0) {
    hipLaunchKernelGGL(sentinel_fill, dim3((TB_ + 255) / 256), dim3(256), 0, stream,
                       outp, -(20000 + badi));
    return;
  }

  const int*   x      = (const int*)d_in[0];
  const int*   lens   = (const int*)d_in[1];
  const float* emb    = (const float*)d_in[2];
  const float* Wih0   = (const float*)d_in[3];
  const float* Whh0   = (const float*)d_in[4];
  const float* b0     = (const float*)d_in[5];
  const float* Wih1   = (const float*)d_in[6];
  const float* Whh1   = (const float*)d_in[7];
  const float* b1     = (const float*)d_in[8];
  const float* Wout   = (const float*)d_in[9];
  const float* bout   = (const float*)d_in[10];
  const float* trans  = (const float*)d_in[11];
  const float* startv = (const float*)d_in[12];
  const float* endv   = (const float*)d_in[13];

  const size_t sz_whh = (size_t)524288 * 4;   // 2 MiB per layer (bijective repack)

  const size_t need =
      (size_t)TB_ * 2048 * 4      // xg
    + (size_t)TB_ * EPAD * 4     // xsA
    + (size_t)TB_ * 512 * 4      // outh
    + (size_t)2048 * EPAD * 4    // B0t
    + (size_t)64 * 512 * 4       // Bot
    + 2 * sz_whh                 // whh0L + whh1L
    + 64 * 4                     // biaso
    + (size_t)TB_ * 64 * 4       // emis
    + 64;                        // diag

  if (ws_size < need) {
    hipLaunchKernelGGL(sentinel_fill, dim3((TB_ + 255) / 256), dim3(256), 0, stream,
                       outp, -(int)(10000 + (ws_size >> 20)));
    return;
  }

  char* w = (char*)d_ws;
  float* xg    = (float*)w;  w += (size_t)TB_ * 2048 * 4;
  float* xsA   = (float*)w;  w += (size_t)TB_ * EPAD * 4;
  float* outh  = (float*)w;  w += (size_t)TB_ * 512 * 4;
  float* B0t   = (float*)w;  w += (size_t)2048 * EPAD * 4;
  float* Bot   = (float*)w;  w += (size_t)64 * 512 * 4;
  float* whh0L = (float*)w;  w += sz_whh;
  float* whh1L = (float*)w;  w += sz_whh;
  float* biaso = (float*)w;  w += 64 * 4;
  float* emis  = (float*)w;  w += (size_t)TB_ * 64 * 4;
  int*   diag  = (int*)w;    w += 64;

  hipLaunchKernelGGL(diag_init, dim3(1), dim3(64), 0, stream, diag);
  hipLaunchKernelGGL(prep_embed, dim3(TB_), dim3(64), 0, stream, x, emb, xsA);
  hipLaunchKernelGGL(prep_b0t, dim3((2048 * EPAD + 255) / 256), dim3(256), 0, stream, Wih0, B0t);
  hipLaunchKernelGGL(prep_bot64, dim3(128), dim3(256), 0, stream, Wout, Bot, bout, biaso);
  hipLaunchKernelGGL(prep_whh2, dim3(2048), dim3(256), 0, stream, Whh0, whh0L);
  hipLaunchKernelGGL(prep_whh2, dim3(2048), dim3(256), 0, stream, Whh1, whh1L);

  // layer 0
  hipLaunchKernelGGL(gemm_f32, dim3(256 * 32), dim3(256), 0, stream,
                     xsA, EPAD, B0t, EPAD, xg, 2048, b0, 32, EPAD);
  hipLaunchKernelGGL(lstm_rec, dim3(128), dim3(512), 0, stream, xg, whh0L, outh, lens);
  // layer 1 (Wih1/b1 used directly: [2048][512] row-major, K=512)
  hipLaunchKernelGGL(gemm_f32, dim3(256 * 32), dim3(256), 0, stream,
                     outh, 512, Wih1, 512, xg, 2048, b1, 32, 512);
  hipLaunchKernelGGL(lstm_rec, dim3(128), dim3(512), 0, stream, xg, whh1L, outh, lens);
  // emissions (N padded to 64) + decode
  hipLaunchKernelGGL(gemm_f32, dim3(256), dim3(256), 0, stream,
                     outh, 512, Bot, 512, emis, 64, biaso, 1, 512);
  hipLaunchKernelGGL(check_nan, dim3(256), dim3(256), 0, stream,
                     emis, (long)TB_ * 64, diag);
  hipLaunchKernelGGL(viterbi, dim3(B_), dim3(64), 0, stream,
                     emis, trans, startv, endv, lens, outp);
  hipLaunchKernelGGL(verdict, dim3(1), dim3(64), 0, stream, diag, outp);
}

// Round 2
// 4778.437 us; speedup vs baseline: 4.6519x; 4.6519x over previous
//
#include <hip/hip_runtime.h>
#include <stdint.h>

// BiLSTM-CRF on gfx950 — fp32 inputs (jax default). All math fp32 (validated
// R4 absmax 0.0). R8: back to 1024-thread lstm_rec (R6 shape) with
// (a) __launch_bounds__(1024,4) -> honest 128-VGPR cap, KR=64 weights REALLY
//     resident (R6/R7 both spilled to scratch; R7's spill went to HBM = 6.5 GB
//     FETCH),
// (b) h broadcast via __builtin_amdgcn_readlane (wave-uniform h -> SGPR operand
//     in v_fmac) replacing 64 uniform ds_read_b128/wave/step,
// (c) KL=12 weight floats/row cached in LDS (48 KiB), 180 streamed from L2
//     with a simple bounded-unroll loop (no hand prefetch arrays).

#define T_ 256
#define B_ 64
#define EPAD 304
#define KTAG 20
#define TB_ (T_ * B_)

// lstm_rec weight partition (per gate row of 256 k):
#define KR 64                        // k resident in VGPRs
#define KL 12                        // k cached in LDS (KLQ quads)
#define KLQ 3
#define NQS 45                       // streamed float4 quads (180 k)
#define WLDS_OFF (2 * KR * 1024)                     // 131072 floats
#define WSTR_OFF (WLDS_OFF + 2 * KLQ * 1024 * 4)     // 155648 floats
// total whhL floats = WSTR_OFF + 2*NQS*1024*4 = 524288 (2 MiB)

__device__ __forceinline__ float rlane(float v, int l) {
  return __int_as_float(__builtin_amdgcn_readlane(__float_as_int(v), l));
}

// ---------------- prep ----------------

__global__ void prep_embed(const int* __restrict__ x, const float* __restrict__ emb,
                           float* __restrict__ xsA) {
  int r = blockIdx.x;
  int tok = x[r];
  const float* src = emb + (size_t)tok * 300;
  for (int e = threadIdx.x; e < EPAD; e += 64)
    xsA[(size_t)r * EPAD + e] = (e < 300) ? src[e] : 0.f;
}

// B0t[2048][304]: Wih0 [2*1024,300] K-padded to 304.
__global__ void prep_b0t(const float* __restrict__ Wih0, float* __restrict__ B0t) {
  int idx = blockIdx.x * 256 + threadIdx.x;
  if (idx >= 2048 * EPAD) return;
  int n = idx / EPAD, k = idx % EPAD;
  B0t[idx] = (k < 300) ? Wih0[(size_t)n * 300 + k] : 0.f;
}

// Bot[64][512]: W_out [20,512] rows padded to 64; biaso[64] likewise.
__global__ void prep_bot64(const float* __restrict__ Wout, float* __restrict__ Bot,
                           const float* __restrict__ bout, float* __restrict__ biaso) {
  int idx = blockIdx.x * 256 + threadIdx.x;   // 64*512
  int n = idx >> 9, k = idx & 511;
  Bot[idx] = (n < KTAG) ? Wout[(size_t)n * 512 + k] : 0.f;
  if (idx < 64) biaso[idx] = (idx < KTAG) ? bout[idx] : 0.f;
}

// Whh [2][1024 rows][256 k] -> whhL; thread tg owns row (tg&3)*256 + (tg>>2).
// Regions: resident [d][k<KR][tg]; LDS [d][q][tg][4] (k KR..KR+KL);
// streamed [d][q][tg][4] (k KR+KL..255).
__global__ void prep_whh2(const float* __restrict__ Whh, float* __restrict__ whhL) {
  int idx = blockIdx.x * 256 + threadIdx.x;   // 524288
  int d = idx >> 18, rem = idx & 262143, k = rem >> 10, tg = rem & 1023;
  int row = (tg & 3) * 256 + (tg >> 2);
  float v = Whh[(size_t)d * 262144 + (size_t)row * 256 + k];
  if (k < KR) {
    whhL[(size_t)(d * KR + k) * 1024 + tg] = v;
  } else if (k < KR + KL) {
    int kk = k - KR, q = kk >> 2, e = kk & 3;
    whhL[WLDS_OFF + (size_t)((d * KLQ + q) * 1024 + tg) * 4 + e] = v;
  } else {
    int kk = k - KR - KL, q = kk >> 2, e = kk & 3;
    whhL[WSTR_OFF + (size_t)((d * NQS + q) * 1024 + tg) * 4 + e] = v;
  }
}

// ---------------- fp32 GEMM: C[M,N] = A[M,K] * Bt[N,K]^T + bias ----------------
// 64x64 tile, BK=16, 256 threads, 4x4 outputs/thread (R4-validated).
__global__ __launch_bounds__(256) void gemm_f32(
    const float* __restrict__ A, int lda, const float* __restrict__ Bt, int ldb,
    float* __restrict__ C, int ldc, const float* __restrict__ bias,
    int ntn, int K) {
  const int tm = blockIdx.x / ntn, tn = blockIdx.x % ntn;
  const int m0 = tm * 64, n0 = tn * 64;
  __shared__ __align__(16) float As[16][64];
  __shared__ __align__(16) float Bs[16][64];
  const int tid = threadIdx.x;
  const int mm = tid >> 2, kq = (tid & 3) * 4;
  const int tx = tid & 15, ty = tid >> 4;
  float acc[4][4] = {};
  for (int k0 = 0; k0 < K; k0 += 16) {
    float4 av = *(const float4*)&A[(size_t)(m0 + mm) * lda + k0 + kq];
    float4 bv = *(const float4*)&Bt[(size_t)(n0 + mm) * ldb + k0 + kq];
    __syncthreads();                       // guard prev-iter LDS reads
    As[kq + 0][mm] = av.x; As[kq + 1][mm] = av.y;
    As[kq + 2][mm] = av.z; As[kq + 3][mm] = av.w;
    Bs[kq + 0][mm] = bv.x; Bs[kq + 1][mm] = bv.y;
    Bs[kq + 2][mm] = bv.z; Bs[kq + 3][mm] = bv.w;
    __syncthreads();
#pragma unroll
    for (int kk = 0; kk < 16; ++kk) {
      float4 a4 = *(const float4*)&As[kk][ty * 4];
      float4 b4 = *(const float4*)&Bs[kk][tx * 4];
      acc[0][0] += a4.x * b4.x; acc[0][1] += a4.x * b4.y;
      acc[0][2] += a4.x * b4.z; acc[0][3] += a4.x * b4.w;
      acc[1][0] += a4.y * b4.x; acc[1][1] += a4.y * b4.y;
      acc[1][2] += a4.y * b4.z; acc[1][3] += a4.y * b4.w;
      acc[2][0] += a4.z * b4.x; acc[2][1] += a4.z * b4.y;
      acc[2][2] += a4.z * b4.z; acc[2][3] += a4.z * b4.w;
      acc[3][0] += a4.w * b4.x; acc[3][1] += a4.w * b4.y;
      acc[3][2] += a4.w * b4.z; acc[3][3] += a4.w * b4.w;
    }
  }
#pragma unroll
  for (int i = 0; i < 4; ++i)
#pragma unroll
    for (int j = 0; j < 4; ++j)
      C[(size_t)(m0 + ty * 4 + i) * ldc + n0 + tx * 4 + j] =
          acc[i][j] + bias[n0 + tx * 4 + j];
}

// ---------------- persistent LSTM recurrence (fp32) ----------------
// One WG (1024 threads, 16 waves, launch_bounds(1024,4) -> 128 VGPR cap) per
// (b,dir). Thread tg owns gate row (tg&3)*256 + (tg>>2). Per step: each wave
// loads h once (1 ds_read_b128, 4 floats/lane) and broadcasts h[k] via
// v_readlane -> SGPR operand in v_fmac (no LDS broadcast wall). Weights:
// KR=64 in VGPRs, KL=12 in LDS, 180 streamed from L2. One barrier/step.
__global__ __launch_bounds__(1024, 4) void lstm_rec(
    const float* __restrict__ xg, const float* __restrict__ whhL,
    float* __restrict__ out, const int* __restrict__ lens) {
  const int wg = blockIdx.x, dir = wg & 1, b = wg >> 1;
  const int len = lens[b];
  const int tg = threadIdx.x;
  const int j = tg >> 2, gt = tg & 3;
  const int row = gt * 256 + j;

  // resident weights k = 0..KR-1
  float wres[KR];
#pragma unroll
  for (int k = 0; k < KR; ++k)
    wres[k] = whhL[(size_t)(dir * KR + k) * 1024 + tg];

  __shared__ __align__(16) float4 wlds[KLQ][1024];   // 48 KiB, k = KR..KR+KL-1
  __shared__ __align__(16) float hsd[2][256];
#pragma unroll
  for (int q = 0; q < KLQ; ++q)
    wlds[q][tg] = *(const float4*)&whhL[WLDS_OFF + (size_t)((dir * KLQ + q) * 1024 + tg) * 4];
  if (tg < 256) hsd[0][tg] = 0.f;
  float c = 0.f;
  __syncthreads();

  // streamed base: k = KR+KL..255, layout [d][q][tg][4]
  const float* sp = whhL + WSTR_OFF + (size_t)dir * NQS * 4096 + (size_t)tg * 4;

  const int lane = tg & 63, qb = lane & ~3;

  for (int s = 0; s < len; ++s) {
    const int t = dir ? (len - 1 - s) : s;   // bwd consumes & writes reversed pos
    const int rp = t * B_ + b;
    float xv = xg[(size_t)rp * 2048 + dir * 1024 + row];
    // wave-local h copy: lane l holds h[4l..4l+3]
    float4 hv = *(const float4*)&hsd[s & 1][lane * 4];

    float acc0 = 0.f, acc1 = 0.f;
    // resident k-quads 0..15
#pragma unroll
    for (int q = 0; q < KR / 4; ++q) {
      float b0 = rlane(hv.x, q), b1 = rlane(hv.y, q);
      float b2 = rlane(hv.z, q), b3 = rlane(hv.w, q);
      acc0 += wres[4 * q + 0] * b0 + wres[4 * q + 1] * b1;
      acc1 += wres[4 * q + 2] * b2 + wres[4 * q + 3] * b3;
    }
    // LDS k-quads (global quads KR/4 .. KR/4+KLQ-1)
#pragma unroll
    for (int q3 = 0; q3 < KLQ; ++q3) {
      int q = KR / 4 + q3;
      float4 wl = wlds[q3][tg];
      float b0 = rlane(hv.x, q), b1 = rlane(hv.y, q);
      float b2 = rlane(hv.z, q), b3 = rlane(hv.w, q);
      acc0 += wl.x * b0 + wl.y * b1;
      acc1 += wl.z * b2 + wl.w * b3;
    }
    // streamed k-quads (global quads KR/4+KLQ .. 63)
#pragma unroll 5
    for (int qq = 0; qq < NQS; ++qq) {
      int q = KR / 4 + KLQ + qq;
      float4 wv = *(const float4*)(sp + (size_t)qq * 4096);
      float b0 = rlane(hv.x, q), b1 = rlane(hv.y, q);
      float b2 = rlane(hv.z, q), b3 = rlane(hv.w, q);
      acc0 += wv.x * b0 + wv.y * b1;
      acc1 += wv.z * b2 + wv.w * b3;
    }

    float a = acc0 + acc1 + xv;
    float v1 = __shfl(a, qb | 1);
    float v2 = __shfl(a, qb | 2);
    float v3 = __shfl(a, qb | 3);
    if (gt == 0) {
      float si = 1.f / (1.f + expf(-a));     // i
      float sf = 1.f / (1.f + expf(-v1));    // f
      float so = 1.f / (1.f + expf(-v3));    // o
      c = sf * c + si * tanhf(v2);           // g = v2
      float h = so * tanhf(c);
      hsd[(s + 1) & 1][j] = h;
      out[(size_t)rp * 512 + dir * 256 + j] = h;
    }
    __syncthreads();                          // one barrier per step
  }
  for (int t = len; t < T_; ++t)              // pack_padded: padded outputs zero
    if (gt == 0) out[(size_t)(t * B_ + b) * 512 + dir * 256 + j] = 0.f;
}

// ---------------- Viterbi (one wave per batch; ref fp-op order) ----------------
__global__ __launch_bounds__(64) void viterbi(
    const float* __restrict__ emis, const float* __restrict__ trans,
    const float* __restrict__ startv, const float* __restrict__ endv,
    const int* __restrict__ lens, int* __restrict__ outp) {
  int b = blockIdx.x, lane = threadIdx.x;
  __shared__ float tr[KTAG * KTAG];
  __shared__ float fin[KTAG];
  __shared__ unsigned char hist[T_ * KTAG];
  for (int i = lane; i < KTAG * KTAG; i += 64) tr[i] = trans[i];
  int len = lens[b];
  float score = (lane < KTAG) ? startv[lane] + emis[(size_t)b * 64 + lane] : -3e38f;
  __syncthreads();
  for (int t = 1; t < len; ++t) {
    float e = (lane < KTAG) ? emis[(size_t)(t * B_ + b) * 64 + lane] : 0.f;
    float best = -3e38f; int bp = 0;
    for (int p = 0; p < KTAG; ++p) {         // ascending p + strict '>': first-index
      float cand = (__shfl(score, p) + tr[p * KTAG + lane]) + e;  // ref op order
      if (cand > best) { best = cand; bp = p; }
    }
    if (lane < KTAG) { score = best; hist[t * KTAG + lane] = (unsigned char)bp; }
  }
  if (lane < KTAG) fin[lane] = score + endv[lane];
  __syncthreads();
  if (lane == 0) {
    float bb = -3e38f; int tag = 0;
    for (int p = 0; p < KTAG; ++p)
      if (fin[p] > bb) { bb = fin[p]; tag = p; }
    for (int t = len - 1; t >= 1; --t) {
      outp[t * B_ + b] = tag;
      tag = hist[t * KTAG + tag];
    }
    outp[b] = tag;
  }
  for (int t = len + lane; t < T_; t += 64) outp[t * B_ + b] = 0;
}

// ---------------- diagnostics (slim) ----------------
__global__ void sentinel_fill(int* __restrict__ outp, int val) {
  int i = blockIdx.x * 256 + threadIdx.x;
  if (i < TB_) outp[i] = val;
}
__global__ void diag_init(int* __restrict__ f) { if (threadIdx.x == 0) f[0] = 0; }
__global__ void check_nan(const float* __restrict__ p, long n, int* __restrict__ f) {
  long i0 = (long)blockIdx.x * 256 + threadIdx.x;
  int bad = 0;
  for (long i = i0; i < n; i += (long)gridDim.x * 256)
    if (!(fabsf(p[i]) <= 1e8f)) bad = 1;
  if (bad) atomicOr(&f[0], 1);
}
__global__ void verdict(const int* __restrict__ f, int* __restrict__ outp) {
  if (f[0]) outp[threadIdx.x] = -4096;
}

// ---------------- host ----------------

extern "C" void kernel_launch(void* const* d_in, const int* in_sizes, int n_in,
                              void* d_out, int out_size, void* d_ws, size_t ws_size,
                              hipStream_t stream) {
  int* outp = (int*)d_out;

  static const int exp_sizes[14] = {16384, 64, 15000000, 614400, 524288, 2048,
                                    1048576, 524288, 2048, 10240, 20, 400, 20, 20};
  int badi = (n_in == 14) ? -1 : 14;
  if (badi < 0)
    for (int i = 0; i < 14; ++i)
      if (in_sizes[i] != exp_sizes[i]) { badi = i; break; }
  if (badi >= 0) {
    hipLaunchKernelGGL(sentinel_fill, dim3((TB_ + 255) / 256), dim3(256), 0, stream,
                       outp, -(20000 + badi));
    return;
  }

  const int*   x      = (const int*)d_in[0];
  const int*   lens   = (const int*)d_in[1];
  const float* emb    = (const float*)d_in[2];
  const float* Wih0   = (const float*)d_in[3];
  const float* Whh0   = (const float*)d_in[4];
  const float* b0     = (const float*)d_in[5];
  const float* Wih1   = (const float*)d_in[6];
  const float* Whh1   = (const float*)d_in[7];
  const float* b1     = (const float*)d_in[8];
  const float* Wout   = (const float*)d_in[9];
  const float* bout   = (const float*)d_in[10];
  const float* trans  = (const float*)d_in[11];
  const float* startv = (const float*)d_in[12];
  const float* endv   = (const float*)d_in[13];

  const size_t sz_whh = (size_t)524288 * 4;   // 2 MiB per layer (bijective repack)

  const size_t need =
      (size_t)TB_ * 2048 * 4      // xg
    + (size_t)TB_ * EPAD * 4     // xsA
    + (size_t)TB_ * 512 * 4      // outh
    + (size_t)2048 * EPAD * 4    // B0t
    + (size_t)64 * 512 * 4       // Bot
    + 2 * sz_whh                 // whh0L + whh1L
    + 64 * 4                     // biaso
    + (size_t)TB_ * 64 * 4       // emis
    + 64;                        // diag

  if (ws_size < need) {
    hipLaunchKernelGGL(sentinel_fill, dim3((TB_ + 255) / 256), dim3(256), 0, stream,
                       outp, -(int)(10000 + (ws_size >> 20)));
    return;
  }

  char* w = (char*)d_ws;
  float* xg    = (float*)w;  w += (size_t)TB_ * 2048 * 4;
  float* xsA   = (float*)w;  w += (size_t)TB_ * EPAD * 4;
  float* outh  = (float*)w;  w += (size_t)TB_ * 512 * 4;
  float* B0t   = (float*)w;  w += (size_t)2048 * EPAD * 4;
  float* Bot   = (float*)w;  w += (size_t)64 * 512 * 4;
  float* whh0L = (float*)w;  w += sz_whh;
  float* whh1L = (float*)w;  w += sz_whh;
  float* biaso = (float*)w;  w += 64 * 4;
  float* emis  = (float*)w;  w += (size_t)TB_ * 64 * 4;
  int*   diag  = (int*)w;    w += 64;

  hipLaunchKernelGGL(diag_init, dim3(1), dim3(64), 0, stream, diag);
  hipLaunchKernelGGL(prep_embed, dim3(TB_), dim3(64), 0, stream, x, emb, xsA);
  hipLaunchKernelGGL(prep_b0t, dim3((2048 * EPAD + 255) / 256), dim3(256), 0, stream, Wih0, B0t);
  hipLaunchKernelGGL(prep_bot64, dim3(128), dim3(256), 0, stream, Wout, Bot, bout, biaso);
  hipLaunchKernelGGL(prep_whh2, dim3(2048), dim3(256), 0, stream, Whh0, whh0L);
  hipLaunchKernelGGL(prep_whh2, dim3(2048), dim3(256), 0, stream, Whh1, whh1L);

  // layer 0
  hipLaunchKernelGGL(gemm_f32, dim3(256 * 32), dim3(256), 0, stream,
                     xsA, EPAD, B0t, EPAD, xg, 2048, b0, 32, EPAD);
  hipLaunchKernelGGL(lstm_rec, dim3(128), dim3(1024), 0, stream, xg, whh0L, outh, lens);
  // layer 1 (Wih1/b1 used directly: [2048][512] row-major, K=512)
  hipLaunchKernelGGL(gemm_f32, dim3(256 * 32), dim3(256), 0, stream,
                     outh, 512, Wih1, 512, xg, 2048, b1, 32, 512);
  hipLaunchKernelGGL(lstm_rec, dim3(128), dim3(1024), 0, stream, xg, whh1L, outh, lens);
  // emissions (N padded to 64) + decode
  hipLaunchKernelGGL(gemm_f32, dim3(256), dim3(256), 0, stream,
                     outh, 512, Bot, 512, emis, 64, biaso, 1, 512);
  hipLaunchKernelGGL(check_nan, dim3(256), dim3(256), 0, stream,
                     emis, (long)TB_ * 64, diag);
  hipLaunchKernelGGL(viterbi, dim3(B_), dim3(64), 0, stream,
                     emis, trans, startv, endv, lens, outp);
  hipLaunchKernelGGL(verdict, dim3(1), dim3(64), 0, stream, diag, outp);
}